// Round 15
// baseline (2879.597 us; speedup 1.0000x reference)
//
#include <hip/hip_runtime.h>

#define TT  64
#define BSZ 512
#define ISZ 512
#define HSZ 1024

typedef short bf16x8 __attribute__((ext_vector_type(8)));
typedef float f32x4 __attribute__((ext_vector_type(4)));
typedef unsigned short u16x8 __attribute__((ext_vector_type(8)));

typedef const __attribute__((address_space(1))) unsigned int* gas_t;
typedef __attribute__((address_space(3))) unsigned int* las_t;

__device__ __forceinline__ unsigned short f2bf(float f) {
    unsigned int u = __float_as_uint(f);
    unsigned int r = u + 0x7FFFu + ((u >> 16) & 1u);   // RNE
    return (unsigned short)(r >> 16);
}
__device__ __forceinline__ float bf2f(unsigned short u) {
    return __uint_as_float(((unsigned int)u) << 16);
}

__global__ void cast_f32_to_bf16(const float* __restrict__ in,
                                 unsigned short* __restrict__ out, int n8) {
    int i = blockIdx.x * blockDim.x + threadIdx.x;
    if (i >= n8) return;
    const float4* p = (const float4*)(in + (size_t)i * 8);
    float4 v0 = p[0], v1 = p[1];
    u16x8 o;
    o[0] = f2bf(v0.x); o[1] = f2bf(v0.y); o[2] = f2bf(v0.z); o[3] = f2bf(v0.w);
    o[4] = f2bf(v1.x); o[5] = f2bf(v1.y); o[6] = f2bf(v1.z); o[7] = f2bf(v1.w);
    *(u16x8*)(out + (size_t)i * 8) = o;
}

__global__ void bias_combine(const float* __restrict__ a,
                             const float* __restrict__ b,
                             float* __restrict__ o) {
    int i = blockIdx.x * blockDim.x + threadIdx.x;
    if (i < 4 * HSZ) o[i] = a[i] + b[i];
}

__global__ void zero_arr(int* p, int n) {
    int i = blockIdx.x * blockDim.x + threadIdx.x;
    if (i < n) p[i] = 0;
}

// ---------------- Phase 1: XG[t] = x_t @ Wih^T + bias, bf16 -----------------
// Consumer layout for the NEW phase 2: [t][x(8)][j(32)][tid(512)][16(g*4+r)].
__global__ __launch_bounds__(256) void xg_gemm(
    const unsigned short* __restrict__ xb,    // [TT,512,512] bf16
    const unsigned short* __restrict__ Wihb,  // [4096,512] bf16
    const float* __restrict__ bias,           // [4096]
    unsigned short* __restrict__ XG)
{
    __shared__ unsigned short Ab[2][128 * 64];
    __shared__ unsigned short Wb[2][128 * 64];

    const int t   = blockIdx.x >> 7;
    const int jb  = blockIdx.x & 127;
    const int xcd = jb & 7;
    const int idx = jb >> 3;
    const int hh0 = (xcd * 4 + (idx & 3)) * 32;
    const int bb0 = (idx >> 2) * 128;

    const unsigned short* A = xb + (size_t)t * BSZ * ISZ;

    const int lane = threadIdx.x & 63;
    const int wv   = threadIdx.x >> 6;
    const int wx   = wv & 1;
    const int wy   = wv >> 1;
    const int lr   = lane & 15;
    const int kq   = lane >> 4;

    const f32x4 z = {0.f, 0.f, 0.f, 0.f};
    f32x4 acc[4][4];
    #pragma unroll
    for (int m = 0; m < 4; ++m)
        #pragma unroll
        for (int g = 0; g < 4; ++g) acc[m][g] = z;

    auto stage = [&](int k0, unsigned short* Abuf, unsigned short* Wbuf) {
        const int sub = lane >> 3;
        const int swk = ((lane & 7) ^ sub) * 8;
        #pragma unroll
        for (int i = 0; i < 4; ++i) {
            const int tr8 = (wv * 4 + i) * 8;
            const unsigned short* g = A + (size_t)(bb0 + tr8 + sub) * ISZ + k0 + swk;
            __builtin_amdgcn_global_load_lds((gas_t)g, (las_t)(Abuf + tr8 * 64), 16, 0, 0);
        }
        #pragma unroll
        for (int i = 0; i < 4; ++i) {
            const int tr8 = (wv * 4 + i) * 8;
            const int tr = tr8 + sub;
            const int wrow = hh0 + (tr & 31) + (tr >> 5) * 1024;
            const unsigned short* g = Wihb + (size_t)wrow * ISZ + k0 + swk;
            __builtin_amdgcn_global_load_lds((gas_t)g, (las_t)(Wbuf + tr8 * 64), 16, 0, 0);
        }
    };

    stage(0, Ab[0], Wb[0]);
    const int swz = (lr & 7) << 4;
    for (int c = 0; c < 8; ++c) {
        const int buf = c & 1;
        if (c + 1 < 8) {
            stage((c + 1) * 64, Ab[buf ^ 1], Wb[buf ^ 1]);
            asm volatile("s_waitcnt vmcnt(8)" ::: "memory");
        } else {
            asm volatile("s_waitcnt vmcnt(0)" ::: "memory");
        }
        __builtin_amdgcn_sched_barrier(0);
        __builtin_amdgcn_s_barrier();

        const char* Ac = (const char*)Ab[buf];
        const char* Wc = (const char*)Wb[buf];
        #pragma unroll
        for (int ks = 0; ks < 2; ++ks) {
            const int kb = ks * 64 + kq * 16;
            bf16x8 wf[4], af[4];
            #pragma unroll
            for (int g = 0; g < 4; ++g) {
                const int tr = g * 32 + wx * 16 + lr;
                wf[g] = *(const bf16x8*)(Wc + tr * 128 + (kb ^ swz));
            }
            #pragma unroll
            for (int m = 0; m < 4; ++m) {
                const int tr = wy * 64 + m * 16 + lr;
                af[m] = *(const bf16x8*)(Ac + tr * 128 + (kb ^ swz));
            }
            #pragma unroll
            for (int m = 0; m < 4; ++m)
                #pragma unroll
                for (int g = 0; g < 4; ++g)
                    acc[m][g] = __builtin_amdgcn_mfma_f32_16x16x32_bf16(af[m], wf[g], acc[m][g], 0, 0, 0);
        }
        __builtin_amdgcn_s_barrier();
    }

    // ---- epilogue: scatter into [x][j][tid][16] consumer layout ----
    const int n = hh0 + wx * 16 + lr;
    const int jc = n >> 5;            // consumer j (constant per block half)
    float bv[4];
    #pragma unroll
    for (int g = 0; g < 4; ++g) bv[g] = bias[g * HSZ + n];
    unsigned short* XGt = XG + (size_t)t * (8 * 32 * 8192);
    #pragma unroll
    for (int m = 0; m < 4; ++m) {
        const int bg = bb0 + wy * 64 + m * 16;       // + kq*4 + r
        const int x  = bg >> 6;
        const int tid_c = (wx * 4 + m) * 64 + kq * 16 + lr;
        u16x8 o0, o1;
        #pragma unroll
        for (int g = 0; g < 4; ++g)
            #pragma unroll
            for (int r = 0; r < 4; ++r) {
                const unsigned short v = f2bf(acc[m][g][r] + bv[g]);
                if (g < 2) o0[g * 4 + r] = v;
                else       o1[(g - 2) * 4 + r] = v;
            }
        unsigned short* dst = XGt + ((size_t)x * 32 + jc) * 8192 + (size_t)tid_c * 16;
        *(u16x8*)(dst) = o0;
        *(u16x8*)(dst + 8) = o1;
    }
}

// ---------------- Phase 2: 8 independent single-XCD sub-LSTMs ---------------
// 256 blocks, 512 thr = 8 waves (2/SIMD). x = bid&7 (XCD, batch rows
// [x*64,+64)), j = bid>>3 (h-cols [j*32,+32), all 4 gates).
// Wave w: mg = w&3 (16-row frag), hg = w>>2 (16-col half). FULL K per wave
// -> no exchange, no extra barriers. W_hh slice: K-half0 in LDS (128 KB),
// K-half1 direct from global (block-unique 128 KB, L2-resident, prewarmed).
// h slab [64][1024] rotates per (t,x); produced+consumed in ONE L2.
// Sync: 32 same-XCD flags; release store (correct even if XCD mapping
// assumption fails - LLC fallback), relaxed lane-parallel poll.
__global__ __launch_bounds__(512, 2) void lstm_rec(
    const unsigned short* __restrict__ XG,    // [TT][8][32][512][16] bf16
    const unsigned short* __restrict__ Whhb,  // [4096,1024] bf16
    float* __restrict__ out,
    unsigned short* __restrict__ hbs,         // [TT][8][64][1024] bf16
    int* __restrict__ flags)                  // [TT][8][32]
{
    __shared__ unsigned short WhL[128 * 512];   // 128 KiB: K-half0 W slice

    const int tid  = threadIdx.x;
    const int lane = tid & 63;
    const int wv   = tid >> 6;
    const int mg   = wv & 3;         // 16-row frag
    const int hg   = wv >> 2;        // 16-col half
    const int lr   = lane & 15;
    const int kq   = lane >> 4;
    const int x    = blockIdx.x & 7;     // XCD / sub-LSTM
    const int j    = blockIdx.x >> 3;    // h-col group

    // ---- stage K-half0 W slice: row r (=g*32+col32), LDS[r][u]=G[r][u^(r&7)] ----
    #pragma unroll
    for (int i = 0; i < 16; ++i) {
        const int r = wv * 16 + i;                       // 0..127
        const int grow = (r >> 5) * 1024 + j * 32 + (r & 31);
        const int gslot = lane ^ (r & 7);
        const unsigned short* g = Whhb + (size_t)grow * 1024 + (size_t)gslot * 8;
        __builtin_amdgcn_global_load_lds((gas_t)g, (las_t)(WhL + r * 512), 16, 0, 0);
    }

    const int col = j * 32 + hg * 16 + lr;               // global h-col
    const unsigned short* xgtb = XG + ((size_t)x * 32 + j) * 8192 + (size_t)tid * 16;
    const unsigned short* wdir = Whhb + (size_t)(j * 32 + hg * 16 + lr) * 1024 + 512 + kq * 8;

    bf16x8 xg0 = *(const bf16x8*)(xgtb);                 // t = 0
    bf16x8 xg1 = *(const bf16x8*)(xgtb + 8);

    // ---- prewarm direct-W half into L2/L1 (dummy-consume, rule-17) ----
    #pragma unroll
    for (int c = 0; c < 16; ++c)
        #pragma unroll
        for (int g = 0; g < 4; ++g) {
            bf16x8 wf = *(const bf16x8*)(wdir + (size_t)g * (1024 * 1024) + c * 32);
            asm volatile("" :: "v"(wf));
        }

    auto h_gemm = [&](const unsigned short* hp, f32x4 (&acc)[4]) {
        const unsigned short* ar = hp + (size_t)(mg * 16 + lr) * 1024 + kq * 8;
        bf16x8 aA[16], aB[16];
        #pragma unroll
        for (int c = 0; c < 16; ++c) aA[c] = *(const bf16x8*)(ar + c * 32);
        __builtin_amdgcn_sched_barrier(0);
        #pragma unroll
        for (int c = 0; c < 16; ++c) aB[c] = *(const bf16x8*)(ar + (c + 16) * 32);
        __builtin_amdgcn_sched_barrier(0);

        asm volatile("s_waitcnt vmcnt(16)" ::: "memory");   // aA ready
        __builtin_amdgcn_sched_barrier(0);
        #pragma unroll
        for (int c = 0; c < 16; ++c) {                      // K-half0: W from LDS
            const int u0 = c * 4 + kq;
            #pragma unroll
            for (int g = 0; g < 4; ++g) {
                const int rr = g * 32 + hg * 16 + lr;
                bf16x8 wf = *(const bf16x8*)((const char*)WhL + rr * 1024 + ((u0 ^ (rr & 7)) << 4));
                acc[g] = __builtin_amdgcn_mfma_f32_16x16x32_bf16(aA[c], wf, acc[g], 0, 0, 0);
            }
        }
        __builtin_amdgcn_sched_barrier(0);
        asm volatile("s_waitcnt vmcnt(0)" ::: "memory");    // aB ready
        __builtin_amdgcn_sched_barrier(0);
        #pragma unroll
        for (int c = 0; c < 16; ++c) {                      // K-half1: W direct (L2-hot)
            #pragma unroll
            for (int g = 0; g < 4; ++g) {
                bf16x8 wf = *(const bf16x8*)(wdir + (size_t)g * (1024 * 1024) + c * 32);
                acc[g] = __builtin_amdgcn_mfma_f32_16x16x32_bf16(aB[c], wf, acc[g], 0, 0, 0);
            }
        }
    };

    asm volatile("s_waitcnt vmcnt(0)" ::: "memory");
    __syncthreads();

    float* hn = out + (size_t)TT * BSZ * HSZ;
    float* cn = hn + (size_t)BSZ * HSZ;
    f32x4 creg = {0.f, 0.f, 0.f, 0.f};
    const int rl0 = mg * 16 + kq * 4;                    // first of this thread's 4 rows

    for (int t = 0; t < TT; ++t) {
        f32x4 acc[4];
        #pragma unroll
        for (int g = 0; g < 4; ++g) acc[g] = (f32x4){0.f, 0.f, 0.f, 0.f};
        if (t > 0) h_gemm(hbs + ((size_t)(t - 1) * 8 + x) * 65536, acc);

        // ---- LSTM pointwise (each thread: 4 rows x 1 col, all 4 gates) ----
        unsigned short* hslab = hbs + ((size_t)t * 8 + x) * 65536;
        float hv[4];
        #pragma unroll
        for (int r = 0; r < 4; ++r) {
            float gi = acc[0][r] + bf2f((unsigned short)xg0[r]);
            float gf = acc[1][r] + bf2f((unsigned short)xg0[4 + r]);
            float gg = acc[2][r] + bf2f((unsigned short)xg1[r]);
            float go = acc[3][r] + bf2f((unsigned short)xg1[4 + r]);
            float ig = 1.f / (1.f + __expf(-gi));
            float fg = 1.f / (1.f + __expf(-gf));
            float gv = 1.f - 2.f / (__expf(2.f * gg) + 1.f);
            float og = 1.f / (1.f + __expf(-go));
            float cnew = fg * creg[r] + ig * gv;
            float h = og * (1.f - 2.f / (__expf(2.f * cnew) + 1.f));
            creg[r] = cnew;
            hv[r] = h;
            hslab[(size_t)(rl0 + r) * 1024 + col] = f2bf(h);
        }
        __syncthreads();   // all waves' h stores drained to L2

        float* outt = out + (size_t)t * BSZ * HSZ;
        if (t + 1 < TT) {
            // arrival: release store (wbl2 covers cross-XCD fallback)
            if (tid == 0)
                __hip_atomic_store(flags + ((size_t)t * 8 + x) * 32 + j, 1,
                                   __ATOMIC_RELEASE, __HIP_MEMORY_SCOPE_AGENT);
            // filler: deferred out stores + xg(t+1) prefetch
            #pragma unroll
            for (int r = 0; r < 4; ++r)
                outt[(size_t)(x * 64 + rl0 + r) * HSZ + col] = hv[r];
            const unsigned short* xgn = xgtb + (size_t)(t + 1) * (8 * 32 * 8192);
            xg0 = *(const bf16x8*)(xgn);
            xg1 = *(const bf16x8*)(xgn + 8);
            // lane-parallel poll over the 32 same-XCD producers
            if (wv == 0 && lane < 32) {
                const int* fp = flags + ((size_t)t * 8 + x) * 32 + lane;
                while (__hip_atomic_load(fp, __ATOMIC_RELAXED, __HIP_MEMORY_SCOPE_AGENT) == 0)
                    __builtin_amdgcn_s_sleep(1);
            }
            __syncthreads();
        } else {
            #pragma unroll
            for (int r = 0; r < 4; ++r) {
                const size_t idx = (size_t)(x * 64 + rl0 + r) * HSZ + col;
                outt[idx] = hv[r];
                hn[idx] = hv[r];
                cn[idx] = creg[r];
            }
        }
    }
}

extern "C" void kernel_launch(void* const* d_in, const int* in_sizes, int n_in,
                              void* d_out, int out_size, void* d_ws, size_t ws_size,
                              hipStream_t stream) {
    const float* input_ = (const float*)d_in[0];
    const float* Wih = (const float*)d_in[3];
    const float* Whh = (const float*)d_in[4];
    const float* bih = (const float*)d_in[5];
    const float* bhh = (const float*)d_in[6];

    char* ws = (char*)d_ws;
    unsigned short* Wihb = (unsigned short*)(ws);                  //   4 MB
    unsigned short* Whhb = (unsigned short*)(ws + (4u << 20));     //   8 MB
    unsigned short* xb   = (unsigned short*)(ws + (12u << 20));    //  32 MB
    float*          bias = (float*)(ws + (44u << 20));             //  16 KB
    int*            flg  = (int*)(ws + (45u << 20));               //  64 KB
    unsigned short* hbs  = (unsigned short*)(ws + (46u << 20));    //  64 MB
    unsigned short* XG   = (unsigned short*)(ws + (110u << 20));   // 256 MB

    zero_arr<<<64, 256, 0, stream>>>(flg, TT * 8 * 32);
    cast_f32_to_bf16<<<1024, 256, 0, stream>>>(Wih, Wihb, (4 * HSZ * ISZ) / 8);
    cast_f32_to_bf16<<<2048, 256, 0, stream>>>(Whh, Whhb, (4 * HSZ * HSZ) / 8);
    cast_f32_to_bf16<<<8192, 256, 0, stream>>>(input_, xb, (TT * BSZ * ISZ) / 8);
    bias_combine<<<16, 256, 0, stream>>>(bih, bhh, bias);

    float* out = (float*)d_out;
    xg_gemm<<<TT * 128, 256, 0, stream>>>(xb, Wihb, bias, XG);
    lstm_rec<<<256, 512, 0, stream>>>(XG, Whhb, out, hbs, flg);
}

// Round 16
// 920.027 us; speedup vs baseline: 3.1299x; 3.1299x over previous
//
#include <hip/hip_runtime.h>

#define TT  64
#define BSZ 512
#define ISZ 512
#define HSZ 1024

typedef short bf16x8 __attribute__((ext_vector_type(8)));
typedef float f32x4 __attribute__((ext_vector_type(4)));
typedef unsigned short u16x8 __attribute__((ext_vector_type(8)));

typedef const __attribute__((address_space(1))) unsigned int* gas_t;
typedef __attribute__((address_space(3))) unsigned int* las_t;

__device__ __forceinline__ unsigned short f2bf(float f) {
    unsigned int u = __float_as_uint(f);
    unsigned int r = u + 0x7FFFu + ((u >> 16) & 1u);   // RNE
    return (unsigned short)(r >> 16);
}
__device__ __forceinline__ float bf2f(unsigned short u) {
    return __uint_as_float(((unsigned int)u) << 16);
}

__global__ void cast_f32_to_bf16(const float* __restrict__ in,
                                 unsigned short* __restrict__ out, int n8) {
    int i = blockIdx.x * blockDim.x + threadIdx.x;
    if (i >= n8) return;
    const float4* p = (const float4*)(in + (size_t)i * 8);
    float4 v0 = p[0], v1 = p[1];
    u16x8 o;
    o[0] = f2bf(v0.x); o[1] = f2bf(v0.y); o[2] = f2bf(v0.z); o[3] = f2bf(v0.w);
    o[4] = f2bf(v1.x); o[5] = f2bf(v1.y); o[6] = f2bf(v1.z); o[7] = f2bf(v1.w);
    *(u16x8*)(out + (size_t)i * 8) = o;
}

__global__ void bias_combine(const float* __restrict__ a,
                             const float* __restrict__ b,
                             float* __restrict__ o) {
    int i = blockIdx.x * blockDim.x + threadIdx.x;
    if (i < 4 * HSZ) o[i] = a[i] + b[i];
}

// ---------------- Phase 1: XG[t] = x_t @ Wih^T + bias, bf16 -----------------
// Consumer layout: [t][mi(4)][ni(64)][tid(512)][16(g*4+r)].
__global__ __launch_bounds__(256) void xg_gemm(
    const unsigned short* __restrict__ xb,    // [TT,512,512] bf16
    const unsigned short* __restrict__ Wihb,  // [4096,512] bf16
    const float* __restrict__ bias,           // [4096]
    unsigned short* __restrict__ XG)
{
    __shared__ unsigned short Ab[2][128 * 64];
    __shared__ unsigned short Wb[2][128 * 64];

    const int t   = blockIdx.x >> 7;
    const int j   = blockIdx.x & 127;
    const int xcd = j & 7;
    const int idx = j >> 3;
    const int hh0 = (xcd * 4 + (idx & 3)) * 32;
    const int bb0 = (idx >> 2) * 128;

    const unsigned short* A = xb + (size_t)t * BSZ * ISZ;

    const int lane = threadIdx.x & 63;
    const int wv   = threadIdx.x >> 6;
    const int wx   = wv & 1;
    const int wy   = wv >> 1;
    const int lr   = lane & 15;
    const int kq   = lane >> 4;

    const f32x4 z = {0.f, 0.f, 0.f, 0.f};
    f32x4 acc[4][4];
    #pragma unroll
    for (int m = 0; m < 4; ++m)
        #pragma unroll
        for (int g = 0; g < 4; ++g) acc[m][g] = z;

    auto stage = [&](int k0, unsigned short* Abuf, unsigned short* Wbuf) {
        const int sub = lane >> 3;
        const int swk = ((lane & 7) ^ sub) * 8;
        #pragma unroll
        for (int i = 0; i < 4; ++i) {
            const int tr8 = (wv * 4 + i) * 8;
            const unsigned short* g = A + (size_t)(bb0 + tr8 + sub) * ISZ + k0 + swk;
            __builtin_amdgcn_global_load_lds((gas_t)g, (las_t)(Abuf + tr8 * 64), 16, 0, 0);
        }
        #pragma unroll
        for (int i = 0; i < 4; ++i) {
            const int tr8 = (wv * 4 + i) * 8;
            const int tr = tr8 + sub;
            const int wrow = hh0 + (tr & 31) + (tr >> 5) * 1024;
            const unsigned short* g = Wihb + (size_t)wrow * ISZ + k0 + swk;
            __builtin_amdgcn_global_load_lds((gas_t)g, (las_t)(Wbuf + tr8 * 64), 16, 0, 0);
        }
    };

    stage(0, Ab[0], Wb[0]);
    const int swz = (lr & 7) << 4;
    for (int c = 0; c < 8; ++c) {
        const int buf = c & 1;
        if (c + 1 < 8) {
            stage((c + 1) * 64, Ab[buf ^ 1], Wb[buf ^ 1]);
            asm volatile("s_waitcnt vmcnt(8)" ::: "memory");
        } else {
            asm volatile("s_waitcnt vmcnt(0)" ::: "memory");
        }
        __builtin_amdgcn_sched_barrier(0);
        __builtin_amdgcn_s_barrier();

        const char* Ac = (const char*)Ab[buf];
        const char* Wc = (const char*)Wb[buf];
        #pragma unroll
        for (int ks = 0; ks < 2; ++ks) {
            const int kb = ks * 64 + kq * 16;
            bf16x8 wf[4], af[4];
            #pragma unroll
            for (int g = 0; g < 4; ++g) {
                const int tr = g * 32 + wx * 16 + lr;
                wf[g] = *(const bf16x8*)(Wc + tr * 128 + (kb ^ swz));
            }
            #pragma unroll
            for (int m = 0; m < 4; ++m) {
                const int tr = wy * 64 + m * 16 + lr;
                af[m] = *(const bf16x8*)(Ac + tr * 128 + (kb ^ swz));
            }
            #pragma unroll
            for (int m = 0; m < 4; ++m)
                #pragma unroll
                for (int g = 0; g < 4; ++g)
                    acc[m][g] = __builtin_amdgcn_mfma_f32_16x16x32_bf16(af[m], wf[g], acc[m][g], 0, 0, 0);
        }
        __builtin_amdgcn_s_barrier();
    }

    // ---- epilogue: scatter into consumer layout ----
    const int n = hh0 + wx * 16 + lr;
    float bv[4];
    #pragma unroll
    for (int g = 0; g < 4; ++g) bv[g] = bias[g * HSZ + n];
    unsigned short* XGt = XG + (size_t)t * (4 * 64 * 8192);
    const size_t slab = ((size_t)(bb0 >> 7) * 64 + (n >> 4)) * 8192;
    #pragma unroll
    for (int m = 0; m < 4; ++m) {
        const int tid_c = ((m & 1) * 4 + wy * 2 + (m >> 1)) * 64 + kq * 16 + lr;
        u16x8 o0, o1;
        #pragma unroll
        for (int g = 0; g < 4; ++g)
            #pragma unroll
            for (int r = 0; r < 4; ++r) {
                const unsigned short v = f2bf(acc[m][g][r] + bv[g]);
                if (g < 2) o0[g * 4 + r] = v;
                else       o1[(g - 2) * 4 + r] = v;
            }
        *(u16x8*)(XGt + slab + (size_t)tid_c * 16) = o0;
        *(u16x8*)(XGt + slab + (size_t)tid_c * 16 + 8) = o1;
    }
}

// ---------------- Phase 2: one launch per step (kernel boundary = barrier) --
// 256 blocks (1/CU via 144KB LDS), 512 thr = 8 waves. mi=bid>>6, ni=bid&63
// (bid%8 = ni&7: the 4 mi-sharers of each W slice land on one XCD -> W
// re-stage dedups in L2). W_hh slice staged to LDS each launch, overlapped
// with the 32 h-loads + xg + c via pinned issue order and counted vmcnt.
// h ping-pongs between two buffers [64 ni][512 b][16 c]; c-state is
// thread-linear f32x4. No flags, no spin, no rotation.
__global__ __launch_bounds__(512, 2) void lstm_step(
    const unsigned short* __restrict__ XG,    // [TT][4][64][512][16] bf16
    const unsigned short* __restrict__ Whhb,  // [4096,1024] bf16
    const unsigned short* __restrict__ hprev, // [64][512][16] bf16
    unsigned short* __restrict__ hnext,       // [64][512][16] bf16
    float* __restrict__ cst,                  // [4*64*512][4] fp32
    float* __restrict__ out,
    int t)
{
    __shared__ unsigned short WhL[64 * 1024];   // 128 KiB W_hh slice
    __shared__ float WS[4096];                  //  16 KiB ks exchange

    const int tid  = threadIdx.x;
    const int lane = tid & 63;
    const int wv   = tid >> 6;
    const int mg   = wv & 3;
    const int ks   = wv >> 2;
    const int lr   = lane & 15;
    const int kq   = lane >> 4;
    const int mi   = blockIdx.x >> 6;
    const int ni   = blockIdx.x & 63;
    const int b0   = mi * 128;
    const int hc0  = ni * 16;

    const int bth = b0 + mg * 32 + ks * 16 + kq * 4;   // this thread's 4 rows
    const int n   = hc0 + lr;
    const unsigned short* xgt = XG + (size_t)t * 2097152
                              + ((size_t)mi * 64 + ni) * 8192 + (size_t)tid * 16;
    float* cth = cst + (((size_t)mi * 64 + ni) * 512 + tid) * 4;

    f32x4 accf[4];
    f32x4 cr;
    bf16x8 xg0, xg1;

    if (t > 0) {
        // ---- group 1: W stage (16 gload_lds) ----
        #pragma unroll
        for (int i = 0; i < 16; ++i) {
            const int li = wv * 16 + i;
            const int r = li >> 1, half = li & 1;
            const int grow = (r >> 4) * HSZ + hc0 + (r & 15);
            const int gslot = (half * 64 + lane) ^ (r & 7);
            const unsigned short* g = Whhb + (size_t)grow * HSZ + (size_t)gslot * 8;
            __builtin_amdgcn_global_load_lds((gas_t)g, (las_t)(WhL + li * 512), 16, 0, 0);
        }
        __builtin_amdgcn_sched_barrier(0);

        // ---- group 2+3: h batches (2 x 16 reg loads) ----
        const int br0 = b0 + mg * 32 + lr;
        bf16x8 a0[2][8], a1[2][8];
        #pragma unroll
        for (int c = 0; c < 8; ++c) {
            const int kc = ks * 512 + c * 32 + kq * 8;
            const size_t base = (size_t)(kc >> 4) * 8192 + (kc & 15);
            a0[0][c] = *(const bf16x8*)(hprev + base + (size_t)br0 * 16);
            a0[1][c] = *(const bf16x8*)(hprev + base + (size_t)(br0 + 16) * 16);
        }
        __builtin_amdgcn_sched_barrier(0);
        #pragma unroll
        for (int c = 0; c < 8; ++c) {
            const int kc = ks * 512 + (c + 8) * 32 + kq * 8;
            const size_t base = (size_t)(kc >> 4) * 8192 + (kc & 15);
            a1[0][c] = *(const bf16x8*)(hprev + base + (size_t)br0 * 16);
            a1[1][c] = *(const bf16x8*)(hprev + base + (size_t)(br0 + 16) * 16);
        }
        __builtin_amdgcn_sched_barrier(0);

        // ---- group 4: xg + c (3 loads) ----
        xg0 = *(const bf16x8*)(xgt);
        xg1 = *(const bf16x8*)(xgt + 8);
        cr  = *(const f32x4*)(cth);
        __builtin_amdgcn_sched_barrier(0);

        // ---- own W writes done (16+16+3 = 35 younger ops remain) ----
        asm volatile("s_waitcnt vmcnt(35)" ::: "memory");
        __builtin_amdgcn_sched_barrier(0);
        __builtin_amdgcn_s_barrier();       // all waves' W writes visible

        const f32x4 z = {0.f, 0.f, 0.f, 0.f};
        f32x4 acc[2][4];
        #pragma unroll
        for (int m = 0; m < 2; ++m)
            #pragma unroll
            for (int g = 0; g < 4; ++g) acc[m][g] = z;

        // ---- batch 0 (ready at vmcnt(19): b1 16 + xg/c 3 remain) ----
        asm volatile("s_waitcnt vmcnt(19)" ::: "memory");
        __builtin_amdgcn_sched_barrier(0);
        #pragma unroll
        for (int c = 0; c < 8; ++c) {
            const int u0 = ks * 64 + c * 4 + kq;
            const int woff = ((u0 ^ (lr & 7)) << 4);
            #pragma unroll
            for (int g = 0; g < 4; ++g) {
                bf16x8 wf = *(const bf16x8*)((const char*)WhL + (g * 16 + lr) * 2048 + woff);
                acc[0][g] = __builtin_amdgcn_mfma_f32_16x16x32_bf16(a0[0][c], wf, acc[0][g], 0, 0, 0);
                acc[1][g] = __builtin_amdgcn_mfma_f32_16x16x32_bf16(a0[1][c], wf, acc[1][g], 0, 0, 0);
            }
        }
        __builtin_amdgcn_sched_barrier(0);
        // ---- batch 1 (ready at vmcnt(3): xg/c remain) ----
        asm volatile("s_waitcnt vmcnt(3)" ::: "memory");
        __builtin_amdgcn_sched_barrier(0);
        #pragma unroll
        for (int c = 0; c < 8; ++c) {
            const int u0 = ks * 64 + (c + 8) * 4 + kq;
            const int woff = ((u0 ^ (lr & 7)) << 4);
            #pragma unroll
            for (int g = 0; g < 4; ++g) {
                bf16x8 wf = *(const bf16x8*)((const char*)WhL + (g * 16 + lr) * 2048 + woff);
                acc[0][g] = __builtin_amdgcn_mfma_f32_16x16x32_bf16(a1[0][c], wf, acc[0][g], 0, 0, 0);
                acc[1][g] = __builtin_amdgcn_mfma_f32_16x16x32_bf16(a1[1][c], wf, acc[1][g], 0, 0, 0);
            }
        }

        // ---- 3-barrier ks exchange (R13) ----
        if (ks == 1) {
            #pragma unroll
            for (int g = 0; g < 4; ++g)
                *(f32x4*)&WS[mg * 1024 + g * 256 + lane * 4] = acc[0][g];
        }
        __syncthreads();
        if (ks == 0) {
            #pragma unroll
            for (int g = 0; g < 4; ++g)
                accf[g] = acc[0][g] + *(const f32x4*)&WS[mg * 1024 + g * 256 + lane * 4];
        }
        __syncthreads();
        if (ks == 0) {
            #pragma unroll
            for (int g = 0; g < 4; ++g)
                *(f32x4*)&WS[mg * 1024 + g * 256 + lane * 4] = acc[1][g];
        }
        __syncthreads();
        if (ks == 1) {
            #pragma unroll
            for (int g = 0; g < 4; ++g)
                accf[g] = acc[1][g] + *(const f32x4*)&WS[mg * 1024 + g * 256 + lane * 4];
        }
    } else {
        xg0 = *(const bf16x8*)(xgt);
        xg1 = *(const bf16x8*)(xgt + 8);
        cr  = (f32x4){0.f, 0.f, 0.f, 0.f};
        #pragma unroll
        for (int g = 0; g < 4; ++g) accf[g] = (f32x4){0.f, 0.f, 0.f, 0.f};
    }

    // ---- LSTM pointwise epilogue (each thread: 4 rows x 1 col) ----
    unsigned short* hslab = hnext + (size_t)ni * 8192;
    float* outt = out + (size_t)t * BSZ * HSZ;
    float* hnp = out + (size_t)TT * BSZ * HSZ;
    float* cnp = hnp + (size_t)BSZ * HSZ;
    #pragma unroll
    for (int r = 0; r < 4; ++r) {
        float gi = accf[0][r] + bf2f((unsigned short)xg0[r]);
        float gf = accf[1][r] + bf2f((unsigned short)xg0[4 + r]);
        float gg = accf[2][r] + bf2f((unsigned short)xg1[r]);
        float go = accf[3][r] + bf2f((unsigned short)xg1[4 + r]);
        float ig = 1.f / (1.f + __expf(-gi));
        float fg = 1.f / (1.f + __expf(-gf));
        float gv = 1.f - 2.f / (__expf(2.f * gg) + 1.f);
        float og = 1.f / (1.f + __expf(-go));
        float cnew = fg * cr[r] + ig * gv;
        float h = og * (1.f - 2.f / (__expf(2.f * cnew) + 1.f));
        cr[r] = cnew;
        const size_t idx = (size_t)(bth + r) * HSZ + n;
        hslab[(size_t)(bth + r) * 16 + lr] = f2bf(h);
        outt[idx] = h;
        if (t == TT - 1) { hnp[idx] = h; cnp[idx] = cnew; }
    }
    *(f32x4*)cth = cr;
}

extern "C" void kernel_launch(void* const* d_in, const int* in_sizes, int n_in,
                              void* d_out, int out_size, void* d_ws, size_t ws_size,
                              hipStream_t stream) {
    const float* input_ = (const float*)d_in[0];
    const float* Wih = (const float*)d_in[3];
    const float* Whh = (const float*)d_in[4];
    const float* bih = (const float*)d_in[5];
    const float* bhh = (const float*)d_in[6];

    char* ws = (char*)d_ws;
    unsigned short* Wihb = (unsigned short*)(ws);                  //   4 MB
    unsigned short* Whhb = (unsigned short*)(ws + (4u << 20));     //   8 MB
    unsigned short* xb   = (unsigned short*)(ws + (12u << 20));    //  32 MB
    float*          bias = (float*)(ws + (44u << 20));             //  16 KB
    unsigned short* hb0  = (unsigned short*)(ws + (45u << 20));    //   1 MB
    unsigned short* hb1  = (unsigned short*)(ws + (46u << 20));    //   1 MB
    float*          cst  = (float*)(ws + (47u << 20));             //   2 MB
    unsigned short* XG   = (unsigned short*)(ws + (50u << 20));    // 256 MB

    cast_f32_to_bf16<<<1024, 256, 0, stream>>>(Wih, Wihb, (4 * HSZ * ISZ) / 8);
    cast_f32_to_bf16<<<2048, 256, 0, stream>>>(Whh, Whhb, (4 * HSZ * HSZ) / 8);
    cast_f32_to_bf16<<<8192, 256, 0, stream>>>(input_, xb, (TT * BSZ * ISZ) / 8);
    bias_combine<<<16, 256, 0, stream>>>(bih, bhh, bias);

    float* out = (float*)d_out;
    xg_gemm<<<TT * 128, 256, 0, stream>>>(xb, Wihb, bias, XG);
    for (int t = 0; t < TT; ++t) {
        const unsigned short* hp = (t & 1) ? hb0 : hb1;
        unsigned short* hx = (t & 1) ? hb1 : hb0;
        lstm_step<<<256, 512, 0, stream>>>(XG, Whhb, hp, hx, cst, out, t);
    }
}